// Round 1
// baseline (187.129 us; speedup 1.0000x reference)
//
#include <hip/hip_runtime.h>

typedef __bf16 bf16x8 __attribute__((ext_vector_type(8)));
typedef float f32x4 __attribute__((ext_vector_type(4)));

__device__ __forceinline__ unsigned short f2bf(float f) {
  union { float f; unsigned u; } x; x.f = f;
  unsigned r = x.u + 0x7FFFu + ((x.u >> 16) & 1u);
  return (unsigned short)(r >> 16);
}

// async global->LDS, 16B per lane; LDS dest must be linear (base + lane*16).
__device__ __forceinline__ void gload_lds16(const void* g, void* l) {
  __builtin_amdgcn_global_load_lds(
      (const __attribute__((address_space(1))) unsigned int*)g,
      (__attribute__((address_space(3))) unsigned int*)l, 16, 0, 0);
}

__device__ __forceinline__ f32x4 mfma16(bf16x8 a, bf16x8 b, f32x4 c) {
  return __builtin_amdgcn_mfma_f32_16x16x32_bf16(a, b, c, 0, 0, 0);
}

// ---------------- q,k,v f32 -> bf16 ----------------
__global__ __launch_bounds__(256) void conv_qkv(const float* __restrict__ q,
                                                const float* __restrict__ k,
                                                const float* __restrict__ v,
                                                unsigned short* __restrict__ dst) {
  const float* src = (blockIdx.y == 0) ? q : (blockIdx.y == 1 ? k : v);
  size_t i = ((size_t)blockIdx.x * 256 + threadIdx.x) * 4;
  float4 f = *(const float4*)(src + i);
  ushort4 u;
  u.x = f2bf(f.x); u.y = f2bf(f.y); u.z = f2bf(f.z); u.w = f2bf(f.w);
  *(ushort4*)(dst + (size_t)blockIdx.y * (4096u * 768u) + i) = u;
}

// ---------------- W (768x768 f32) -> Wt[n][k] bf16 ----------------
__global__ __launch_bounds__(256) void conv_w(const float* __restrict__ W0,
                                              const float* __restrict__ W1,
                                              const float* __restrict__ W2,
                                              const float* __restrict__ W3,
                                              unsigned short* __restrict__ Wt) {
  __shared__ float tile[32][33];
  const float* W = (blockIdx.z == 0) ? W0 : (blockIdx.z == 1) ? W1
                   : (blockIdx.z == 2) ? W2 : W3;
  int tx = threadIdx.x, ty = threadIdx.y;  // 32 x 8
  int n0 = blockIdx.x * 32, k0 = blockIdx.y * 32;
#pragma unroll
  for (int i = 0; i < 4; ++i)
    tile[ty * 4 + i][tx] = W[(size_t)(k0 + ty * 4 + i) * 768 + n0 + tx];
  __syncthreads();
  unsigned short* o = Wt + (size_t)blockIdx.z * 768 * 768;
#pragma unroll
  for (int i = 0; i < 4; ++i)
    o[(size_t)(n0 + ty * 4 + i) * 768 + k0 + tx] = f2bf(tile[tx][ty * 4 + i]);
}

// ---------------- shared GEMM mainloop: 128x128 tile, BK=64 ----------------
// A[M][768] bf16 row-major, B = Wt[n][k] bf16 (k contiguous).
// LDS chunk-XOR swizzle: byte = r*128 + ((chunk ^ (r&7))<<4); staging pre-swizzles
// the GLOBAL source (linear LDS dest, rule 21), reads apply the same XOR.
__device__ __forceinline__ void gemm_core(const unsigned short* __restrict__ A,
                                          const unsigned short* __restrict__ B,
                                          unsigned short* As, unsigned short* Bs,
                                          int m0, int n0, int wm, int wn,
                                          int t, int g, int c16,
                                          f32x4 (&acc)[4][4]) {
  for (int k0 = 0; k0 < 768; k0 += 64) {
    if (k0) __syncthreads();
#pragma unroll
    for (int i = 0; i < 4; ++i) {
      int fc = i * 256 + t;
      int r = fc >> 3, c = (fc & 7) ^ (r & 7);
      gload_lds16(A + (size_t)(m0 + r) * 768 + k0 + c * 8, (char*)As + fc * 16);
      gload_lds16(B + (size_t)(n0 + r) * 768 + k0 + c * 8, (char*)Bs + fc * 16);
    }
    __syncthreads();
#pragma unroll
    for (int kk = 0; kk < 2; ++kk) {
      const int ch = kk * 4 + g;
      bf16x8 a[4], b[4];
#pragma unroll
      for (int mi = 0; mi < 4; ++mi) {
        int r = wm + mi * 16 + c16;
        a[mi] = *(const bf16x8*)((char*)As + r * 128 + ((ch ^ (r & 7)) << 4));
      }
#pragma unroll
      for (int ni = 0; ni < 4; ++ni) {
        int r = wn + ni * 16 + c16;
        b[ni] = *(const bf16x8*)((char*)Bs + r * 128 + ((ch ^ (r & 7)) << 4));
      }
#pragma unroll
      for (int mi = 0; mi < 4; ++mi)
#pragma unroll
        for (int ni = 0; ni < 4; ++ni)
          acc[mi][ni] = mfma16(a[mi], b[ni], acc[mi][ni]);
    }
  }
}

// ---------------- QKV projections (z=0 qh, z=1 kh, z=2 vh-transposed) ----------------
__global__ __launch_bounds__(256) void gemm_qkv(const unsigned short* __restrict__ Abase,
                                                const unsigned short* __restrict__ Wt,
                                                unsigned short* __restrict__ Hq,
                                                unsigned short* __restrict__ Hk,
                                                unsigned short* __restrict__ Hvt) {
  __shared__ unsigned short As[128 * 64], Bs[128 * 64];
  const int z = blockIdx.z;
  const unsigned short* A = Abase + (size_t)z * 4096 * 768;
  const unsigned short* B = Wt + (size_t)z * 768 * 768;
  const int t = threadIdx.x, l = t & 63, wid = t >> 6;
  const int g = l >> 4, c16 = l & 15;
  const int m0 = blockIdx.y * 128, n0 = blockIdx.x * 128;
  const int wm = (wid >> 1) * 64, wn = (wid & 1) * 64;
  f32x4 acc[4][4] = {};
  gemm_core(A, B, As, Bs, m0, n0, wm, wn, t, g, c16, acc);
  if (z < 2) {
    unsigned short* C = (z == 0) ? Hq : Hk;
#pragma unroll
    for (int mi = 0; mi < 4; ++mi)
#pragma unroll
      for (int ni = 0; ni < 4; ++ni) {
        int col = n0 + wn + ni * 16 + c16;
        int row = m0 + wm + mi * 16 + g * 4;
#pragma unroll
        for (int j = 0; j < 4; ++j)
          C[(size_t)(row + j) * 768 + col] = f2bf(acc[mi][ni][j]);
      }
  } else {
    // vhT[(b*768 + col)*1024 + m] : head-major rows, sequence contiguous
#pragma unroll
    for (int mi = 0; mi < 4; ++mi) {
      int rowbase = m0 + wm + mi * 16;
      int bb = rowbase >> 10;
      int mloc = (rowbase & 1023) + g * 4;
#pragma unroll
      for (int ni = 0; ni < 4; ++ni) {
        int col = n0 + wn + ni * 16 + c16;
        ushort4 u;
        u.x = f2bf(acc[mi][ni][0]); u.y = f2bf(acc[mi][ni][1]);
        u.z = f2bf(acc[mi][ni][2]); u.w = f2bf(acc[mi][ni][3]);
        *(ushort4*)(Hvt + (((size_t)(bb * 768 + col)) << 10) + mloc) = u;
      }
    }
  }
}

// ---------------- fused attention: softmax (no max-sub) + post-softmax mask ----------------
__global__ __launch_bounds__(256) void attn(const unsigned short* __restrict__ qh,
                                            const unsigned short* __restrict__ kh,
                                            const unsigned short* __restrict__ vhT,
                                            const float* __restrict__ mask,
                                            unsigned short* __restrict__ xb) {
  __shared__ unsigned short Qs[128 * 64], Ks[64 * 64], Vts[64 * 64], Ps[4 * 32 * 64];
  const int qt = blockIdx.x, h = blockIdx.y, b = blockIdx.z;
  const int t = threadIdx.x, l = t & 63, wid = t >> 6;
  const int g = l >> 4, c16 = l & 15;
#pragma unroll
  for (int i = 0; i < 4; ++i) {
    int fc = i * 256 + t;
    int r = fc >> 3, c = (fc & 7) ^ (r & 7);
    gload_lds16(qh + (size_t)(b * 1024 + qt * 128 + r) * 768 + h * 64 + c * 8,
                (char*)Qs + fc * 16);
  }
  f32x4 o[2][4] = {};
  float lsum[2][4] = {{0.f, 0.f, 0.f, 0.f}, {0.f, 0.f, 0.f, 0.f}};
  const float sc = 0.125f * 1.44269504088896341f;  // SCALE * log2(e)
  unsigned short* Pw = Ps + wid * (32 * 64);
  for (int kv = 0; kv < 16; ++kv) {
    __syncthreads();  // prev-iter LDS reads done (kv=0: drains Q staging)
#pragma unroll
    for (int i = 0; i < 2; ++i) {
      int fc = i * 256 + t;
      int r = fc >> 3, c = (fc & 7) ^ (r & 7);
      gload_lds16(kh + (size_t)(b * 1024 + kv * 64 + r) * 768 + h * 64 + c * 8,
                  (char*)Ks + fc * 16);
      gload_lds16(vhT + ((size_t)(b * 768 + h * 64 + r)) * 1024 + kv * 64 + c * 8,
                  (char*)Vts + fc * 16);
    }
    __syncthreads();
    // S = Q K^T (per wave: 32 q-rows x 64 keys)
    f32x4 p[2][4] = {};
#pragma unroll
    for (int kk = 0; kk < 2; ++kk) {
      const int ch = kk * 4 + g;
      bf16x8 aq[2], bk[4];
#pragma unroll
      for (int mi = 0; mi < 2; ++mi) {
        int r = wid * 32 + mi * 16 + c16;
        aq[mi] = *(const bf16x8*)((char*)Qs + r * 128 + ((ch ^ (r & 7)) << 4));
      }
#pragma unroll
      for (int ni = 0; ni < 4; ++ni) {
        int r = ni * 16 + c16;
        bk[ni] = *(const bf16x8*)((char*)Ks + r * 128 + ((ch ^ (r & 7)) << 4));
      }
#pragma unroll
      for (int mi = 0; mi < 2; ++mi)
#pragma unroll
        for (int ni = 0; ni < 4; ++ni)
          p[mi][ni] = mfma16(aq[mi], bk[ni], p[mi][ni]);
    }
    // exp (no max-sub: logits <= ~6), unmasked row-sum, then post-softmax mask
#pragma unroll
    for (int mi = 0; mi < 2; ++mi) {
#pragma unroll
      for (int j = 0; j < 4; ++j) {
        float e0 = exp2f(p[mi][0][j] * sc);
        float e1 = exp2f(p[mi][1][j] * sc);
        float e2 = exp2f(p[mi][2][j] * sc);
        float e3 = exp2f(p[mi][3][j] * sc);
        p[mi][0][j] = e0; p[mi][1][j] = e1; p[mi][2][j] = e2; p[mi][3][j] = e3;
        float s = e0 + e1 + e2 + e3;
        s += __shfl_xor(s, 1);
        s += __shfl_xor(s, 2);
        s += __shfl_xor(s, 4);
        s += __shfl_xor(s, 8);
        lsum[mi][j] += s;
      }
#pragma unroll
      for (int ni = 0; ni < 4; ++ni) {
        const float* mp = mask +
            ((size_t)(b * 1024 + qt * 128 + wid * 32 + mi * 16 + g * 4)) * 1024 +
            kv * 64 + ni * 16 + c16;
#pragma unroll
        for (int j = 0; j < 4; ++j) {
          float pv = p[mi][ni][j] * mp[(size_t)j * 1024];
          int row = mi * 16 + g * 4 + j, col = ni * 16 + c16;
          *(unsigned short*)((char*)Pw + row * 128 +
                             (((col >> 3) ^ (row & 7)) << 4) + ((col & 7) << 1)) = f2bf(pv);
        }
      }
    }
    asm volatile("s_waitcnt lgkmcnt(0)" ::: "memory");  // P writes visible to own wave
    // O += P @ V
#pragma unroll
    for (int kk = 0; kk < 2; ++kk) {
      const int ch = kk * 4 + g;
      bf16x8 ap[2], bv[4];
#pragma unroll
      for (int mi = 0; mi < 2; ++mi) {
        int r = mi * 16 + c16;
        ap[mi] = *(const bf16x8*)((char*)Pw + r * 128 + ((ch ^ (r & 7)) << 4));
      }
#pragma unroll
      for (int ni = 0; ni < 4; ++ni) {
        int r = ni * 16 + c16;
        bv[ni] = *(const bf16x8*)((char*)Vts + r * 128 + ((ch ^ (r & 7)) << 4));
      }
#pragma unroll
      for (int mi = 0; mi < 2; ++mi)
#pragma unroll
        for (int ni = 0; ni < 4; ++ni)
          o[mi][ni] = mfma16(ap[mi], bv[ni], o[mi][ni]);
    }
  }
#pragma unroll
  for (int mi = 0; mi < 2; ++mi)
#pragma unroll
    for (int ni = 0; ni < 4; ++ni) {
      int col = h * 64 + ni * 16 + c16;
      int row = qt * 128 + wid * 32 + mi * 16 + g * 4;
#pragma unroll
      for (int j = 0; j < 4; ++j)
        xb[((size_t)(b * 1024) + row + j) * 768 + col] = f2bf(o[mi][ni][j] / lsum[mi][j]);
    }
}

// ---------------- output projection + bias, f32 out ----------------
__global__ __launch_bounds__(256) void gemm_proj(const unsigned short* __restrict__ A,
                                                 const unsigned short* __restrict__ B,
                                                 const float* __restrict__ bias,
                                                 float* __restrict__ C) {
  __shared__ unsigned short As[128 * 64], Bs[128 * 64];
  const int t = threadIdx.x, l = t & 63, wid = t >> 6;
  const int g = l >> 4, c16 = l & 15;
  const int m0 = blockIdx.y * 128, n0 = blockIdx.x * 128;
  const int wm = (wid >> 1) * 64, wn = (wid & 1) * 64;
  f32x4 acc[4][4] = {};
  gemm_core(A, B, As, Bs, m0, n0, wm, wn, t, g, c16, acc);
#pragma unroll
  for (int mi = 0; mi < 4; ++mi)
#pragma unroll
    for (int ni = 0; ni < 4; ++ni) {
      int col = n0 + wn + ni * 16 + c16;
      int row = m0 + wm + mi * 16 + g * 4;
      float bv = bias[col];
#pragma unroll
      for (int j = 0; j < 4; ++j)
        C[(size_t)(row + j) * 768 + col] = acc[mi][ni][j] + bv;
    }
}

extern "C" void kernel_launch(void* const* d_in, const int* in_sizes, int n_in,
                              void* d_out, int out_size, void* d_ws, size_t ws_size,
                              hipStream_t stream) {
  const float* q    = (const float*)d_in[0];
  const float* k    = (const float*)d_in[1];
  const float* v    = (const float*)d_in[2];
  const float* mask = (const float*)d_in[3];
  const float* Wq   = (const float*)d_in[4];
  const float* Wk   = (const float*)d_in[5];
  const float* Wv   = (const float*)d_in[6];
  const float* Wp   = (const float*)d_in[7];
  const float* bp   = (const float*)d_in[8];
  float* out = (float*)d_out;

  const size_t MN = (size_t)4096 * 768;   // tokens x channels
  const size_t WW = (size_t)768 * 768;
  unsigned short* qkv_bf = (unsigned short*)d_ws;       // 3*MN
  unsigned short* wt     = qkv_bf + 3 * MN;             // 4*WW (WqT,WkT,WvT,WpT)
  unsigned short* heads  = wt + 4 * WW;                 // qh | kh | vhT, 3*MN
  unsigned short* xb     = heads + 3 * MN;              // attention out, MN

  conv_qkv<<<dim3(3072, 3), 256, 0, stream>>>(q, k, v, qkv_bf);
  conv_w<<<dim3(24, 24, 4), dim3(32, 8), 0, stream>>>(Wq, Wk, Wv, Wp, wt);
  gemm_qkv<<<dim3(6, 32, 3), 256, 0, stream>>>(qkv_bf, wt, heads, heads + MN, heads + 2 * MN);
  attn<<<dim3(8, 12, 4), 256, 0, stream>>>(heads, heads + MN, heads + 2 * MN, mask, xb);
  gemm_proj<<<dim3(6, 32), 256, 0, stream>>>(xb, wt + 3 * WW, bp, out);
}

// Round 2
// 111.976 us; speedup vs baseline: 1.6712x; 1.6712x over previous
//
#include <hip/hip_runtime.h>

typedef __bf16 bf16x8 __attribute__((ext_vector_type(8)));
typedef float f32x4 __attribute__((ext_vector_type(4)));

__device__ __forceinline__ unsigned short f2bf(float f) {
  union { float f; unsigned u; } x; x.f = f;
  unsigned r = x.u + 0x7FFFu + ((x.u >> 16) & 1u);
  return (unsigned short)(r >> 16);
}

// async global->LDS, 16B per lane; LDS dest must be linear (base + lane*16).
__device__ __forceinline__ void gload_lds16(const void* g, void* l) {
  __builtin_amdgcn_global_load_lds(
      (const __attribute__((address_space(1))) unsigned int*)g,
      (__attribute__((address_space(3))) unsigned int*)l, 16, 0, 0);
}

__device__ __forceinline__ f32x4 mfma16(bf16x8 a, bf16x8 b, f32x4 c) {
  return __builtin_amdgcn_mfma_f32_16x16x32_bf16(a, b, c, 0, 0, 0);
}

// ---------------- q,k,v f32 -> bf16 ----------------
__global__ __launch_bounds__(256) void conv_qkv(const float* __restrict__ q,
                                                const float* __restrict__ k,
                                                const float* __restrict__ v,
                                                unsigned short* __restrict__ dst) {
  const float* src = (blockIdx.y == 0) ? q : (blockIdx.y == 1 ? k : v);
  size_t i = ((size_t)blockIdx.x * 256 + threadIdx.x) * 4;
  float4 f = *(const float4*)(src + i);
  ushort4 u;
  u.x = f2bf(f.x); u.y = f2bf(f.y); u.z = f2bf(f.z); u.w = f2bf(f.w);
  *(ushort4*)(dst + (size_t)blockIdx.y * (4096u * 768u) + i) = u;
}

// ---------------- W (768x768 f32) -> Wt[n][k] bf16 ----------------
__global__ __launch_bounds__(256) void conv_w(const float* __restrict__ W0,
                                              const float* __restrict__ W1,
                                              const float* __restrict__ W2,
                                              const float* __restrict__ W3,
                                              unsigned short* __restrict__ Wt) {
  __shared__ float tile[32][33];
  const float* W = (blockIdx.z == 0) ? W0 : (blockIdx.z == 1) ? W1
                   : (blockIdx.z == 2) ? W2 : W3;
  int tx = threadIdx.x, ty = threadIdx.y;  // 32 x 8
  int n0 = blockIdx.x * 32, k0 = blockIdx.y * 32;
#pragma unroll
  for (int i = 0; i < 4; ++i)
    tile[ty * 4 + i][tx] = W[(size_t)(k0 + ty * 4 + i) * 768 + n0 + tx];
  __syncthreads();
  unsigned short* o = Wt + (size_t)blockIdx.z * 768 * 768;
#pragma unroll
  for (int i = 0; i < 4; ++i)
    o[(size_t)(n0 + ty * 4 + i) * 768 + k0 + tx] = f2bf(tile[tx][ty * 4 + i]);
}

// ---------------- shared GEMM mainloop: 128x128 tile, BK=64 ----------------
__device__ __forceinline__ void gemm_core(const unsigned short* __restrict__ A,
                                          const unsigned short* __restrict__ B,
                                          unsigned short* As, unsigned short* Bs,
                                          int m0, int n0, int wm, int wn,
                                          int t, int g, int c16,
                                          f32x4 (&acc)[4][4]) {
  for (int k0 = 0; k0 < 768; k0 += 64) {
    if (k0) __syncthreads();
#pragma unroll
    for (int i = 0; i < 4; ++i) {
      int fc = i * 256 + t;
      int r = fc >> 3, c = (fc & 7) ^ (r & 7);
      gload_lds16(A + (size_t)(m0 + r) * 768 + k0 + c * 8, (char*)As + fc * 16);
      gload_lds16(B + (size_t)(n0 + r) * 768 + k0 + c * 8, (char*)Bs + fc * 16);
    }
    __syncthreads();
#pragma unroll
    for (int kk = 0; kk < 2; ++kk) {
      const int ch = kk * 4 + g;
      bf16x8 a[4], b[4];
#pragma unroll
      for (int mi = 0; mi < 4; ++mi) {
        int r = wm + mi * 16 + c16;
        a[mi] = *(const bf16x8*)((char*)As + r * 128 + ((ch ^ (r & 7)) << 4));
      }
#pragma unroll
      for (int ni = 0; ni < 4; ++ni) {
        int r = wn + ni * 16 + c16;
        b[ni] = *(const bf16x8*)((char*)Bs + r * 128 + ((ch ^ (r & 7)) << 4));
      }
#pragma unroll
      for (int mi = 0; mi < 4; ++mi)
#pragma unroll
        for (int ni = 0; ni < 4; ++ni)
          acc[mi][ni] = mfma16(a[mi], b[ni], acc[mi][ni]);
    }
  }
}

// ---------------- QKV projections (z=0 qh, z=1 kh, z=2 vh-transposed) ----------------
__global__ __launch_bounds__(256) void gemm_qkv(const unsigned short* __restrict__ Abase,
                                                const unsigned short* __restrict__ Wt,
                                                unsigned short* __restrict__ Hq,
                                                unsigned short* __restrict__ Hk,
                                                unsigned short* __restrict__ Hvt) {
  __shared__ unsigned short As[128 * 64], Bs[128 * 64];
  const int z = blockIdx.z;
  const unsigned short* A = Abase + (size_t)z * 4096 * 768;
  const unsigned short* B = Wt + (size_t)z * 768 * 768;
  const int t = threadIdx.x, l = t & 63, wid = t >> 6;
  const int g = l >> 4, c16 = l & 15;
  const int m0 = blockIdx.y * 128, n0 = blockIdx.x * 128;
  const int wm = (wid >> 1) * 64, wn = (wid & 1) * 64;
  f32x4 acc[4][4] = {};
  gemm_core(A, B, As, Bs, m0, n0, wm, wn, t, g, c16, acc);
  if (z < 2) {
    unsigned short* C = (z == 0) ? Hq : Hk;
#pragma unroll
    for (int mi = 0; mi < 4; ++mi)
#pragma unroll
      for (int ni = 0; ni < 4; ++ni) {
        int col = n0 + wn + ni * 16 + c16;
        int row = m0 + wm + mi * 16 + g * 4;
#pragma unroll
        for (int j = 0; j < 4; ++j)
          C[(size_t)(row + j) * 768 + col] = f2bf(acc[mi][ni][j]);
      }
  } else {
    // vhT[(b*768 + col)*1024 + m] : head-major rows, sequence contiguous
#pragma unroll
    for (int mi = 0; mi < 4; ++mi) {
      int rowbase = m0 + wm + mi * 16;
      int bb = rowbase >> 10;
      int mloc = (rowbase & 1023) + g * 4;
#pragma unroll
      for (int ni = 0; ni < 4; ++ni) {
        int col = n0 + wn + ni * 16 + c16;
        ushort4 u;
        u.x = f2bf(acc[mi][ni][0]); u.y = f2bf(acc[mi][ni][1]);
        u.z = f2bf(acc[mi][ni][2]); u.w = f2bf(acc[mi][ni][3]);
        *(ushort4*)(Hvt + (((size_t)(bb * 768 + col)) << 10) + mloc) = u;
      }
    }
  }
}

// ---------------- fused attention, QBLK=64, double-buffered K/V ----------------
// softmax without max-subtraction (logits*scale <= ~6 for this distribution),
// unmasked row-sum, post-softmax multiplicative mask, P via swizzled LDS.
__global__ __launch_bounds__(256) void attn(const unsigned short* __restrict__ qh,
                                            const unsigned short* __restrict__ kh,
                                            const unsigned short* __restrict__ vhT,
                                            const float* __restrict__ mask,
                                            unsigned short* __restrict__ xb) {
  __shared__ unsigned short Qs[64 * 64], Ks[2][64 * 64], Vts[2][64 * 64], Ps[4 * 16 * 64];
  const int qt = blockIdx.x, h = blockIdx.y, b = blockIdx.z;
  const int t = threadIdx.x, l = t & 63, wid = t >> 6;
  const int g = l >> 4, c16 = l & 15;
  // prologue: stage Q + K/V tile 0, drain once
#pragma unroll
  for (int i = 0; i < 2; ++i) {
    int fc = i * 256 + t;
    int r = fc >> 3, c = (fc & 7) ^ (r & 7);
    gload_lds16(qh + (size_t)(b * 1024 + qt * 64 + r) * 768 + h * 64 + c * 8,
                (char*)Qs + fc * 16);
    gload_lds16(kh + (size_t)(b * 1024 + r) * 768 + h * 64 + c * 8,
                (char*)Ks[0] + fc * 16);
    gload_lds16(vhT + ((size_t)(b * 768 + h * 64 + r)) * 1024 + c * 8,
                (char*)Vts[0] + fc * 16);
  }
  asm volatile("s_waitcnt vmcnt(0)" ::: "memory");
  __syncthreads();

  f32x4 o[4] = {};
  float lsum[4] = {0.f, 0.f, 0.f, 0.f};
  const float sc = 0.125f * 1.44269504088896341f;  // SCALE * log2(e)
  unsigned short* Pw = Ps + wid * (16 * 64);
  for (int kv = 0; kv < 16; ++kv) {
    const int cur = kv & 1;
    // issue next K/V tile staging (overlaps with everything below)
    if (kv + 1 < 16) {
#pragma unroll
      for (int i = 0; i < 2; ++i) {
        int fc = i * 256 + t;
        int r = fc >> 3, c = (fc & 7) ^ (r & 7);
        gload_lds16(kh + (size_t)(b * 1024 + (kv + 1) * 64 + r) * 768 + h * 64 + c * 8,
                    (char*)Ks[cur ^ 1] + fc * 16);
        gload_lds16(vhT + ((size_t)(b * 768 + h * 64 + r)) * 1024 + (kv + 1) * 64 + c * 8,
                    (char*)Vts[cur ^ 1] + fc * 16);
      }
    }
    // prefetch mask tile into registers (latency hides under QK^T MFMAs)
    float mreg[4][4];
    const float* mbase = mask + ((size_t)(b * 1024 + qt * 64 + wid * 16 + g * 4)) * 1024 + kv * 64;
#pragma unroll
    for (int ni = 0; ni < 4; ++ni)
#pragma unroll
      for (int j = 0; j < 4; ++j)
        mreg[ni][j] = mbase[(size_t)j * 1024 + ni * 16 + c16];
    // S = Q K^T (per wave: 16 q-rows x 64 keys)
    f32x4 p[4] = {};
#pragma unroll
    for (int kk = 0; kk < 2; ++kk) {
      const int ch = kk * 4 + g;
      int rq = wid * 16 + c16;
      bf16x8 aq = *(const bf16x8*)((char*)Qs + rq * 128 + ((ch ^ (rq & 7)) << 4));
#pragma unroll
      for (int ni = 0; ni < 4; ++ni) {
        int r = ni * 16 + c16;
        bf16x8 bk = *(const bf16x8*)((char*)Ks[cur] + r * 128 + ((ch ^ (r & 7)) << 4));
        p[ni] = mfma16(aq, bk, p[ni]);
      }
    }
    // exp (no max-sub), unmasked row-sum over 64 keys
#pragma unroll
    for (int j = 0; j < 4; ++j) {
      float e0 = exp2f(p[0][j] * sc);
      float e1 = exp2f(p[1][j] * sc);
      float e2 = exp2f(p[2][j] * sc);
      float e3 = exp2f(p[3][j] * sc);
      p[0][j] = e0; p[1][j] = e1; p[2][j] = e2; p[3][j] = e3;
      float s = e0 + e1 + e2 + e3;
      s += __shfl_xor(s, 1);
      s += __shfl_xor(s, 2);
      s += __shfl_xor(s, 4);
      s += __shfl_xor(s, 8);
      lsum[j] += s;
    }
    // post-softmax mask, write P (bf16) into per-wave swizzled LDS
#pragma unroll
    for (int ni = 0; ni < 4; ++ni)
#pragma unroll
      for (int j = 0; j < 4; ++j) {
        float pv = p[ni][j] * mreg[ni][j];
        int row = g * 4 + j, col = ni * 16 + c16;
        *(unsigned short*)((char*)Pw + row * 128 +
                           (((col >> 3) ^ (row & 7)) << 4) + ((col & 7) << 1)) = f2bf(pv);
      }
    asm volatile("s_waitcnt lgkmcnt(0)" ::: "memory");  // own-wave P visibility
    // O += P @ V
#pragma unroll
    for (int kk = 0; kk < 2; ++kk) {
      const int ch = kk * 4 + g;
      int rp = c16;
      bf16x8 ap = *(const bf16x8*)((char*)Pw + rp * 128 + ((ch ^ (rp & 7)) << 4));
#pragma unroll
      for (int ni = 0; ni < 4; ++ni) {
        int r = ni * 16 + c16;
        bf16x8 bv = *(const bf16x8*)((char*)Vts[cur] + r * 128 + ((ch ^ (r & 7)) << 4));
        o[ni] = mfma16(ap, bv, o[ni]);
      }
    }
    // next tile's staging done; all waves finished reading buf[cur]
    asm volatile("s_waitcnt vmcnt(0)" ::: "memory");
    __syncthreads();
  }
#pragma unroll
  for (int ni = 0; ni < 4; ++ni) {
    int col = h * 64 + ni * 16 + c16;
    int row = qt * 64 + wid * 16 + g * 4;
#pragma unroll
    for (int j = 0; j < 4; ++j)
      xb[((size_t)(b * 1024) + row + j) * 768 + col] = f2bf(o[ni][j] / lsum[j]);
  }
}

// ---------------- output projection + bias, f32 out ----------------
__global__ __launch_bounds__(256) void gemm_proj(const unsigned short* __restrict__ A,
                                                 const unsigned short* __restrict__ B,
                                                 const float* __restrict__ bias,
                                                 float* __restrict__ C) {
  __shared__ unsigned short As[128 * 64], Bs[128 * 64];
  const int t = threadIdx.x, l = t & 63, wid = t >> 6;
  const int g = l >> 4, c16 = l & 15;
  const int m0 = blockIdx.y * 128, n0 = blockIdx.x * 128;
  const int wm = (wid >> 1) * 64, wn = (wid & 1) * 64;
  f32x4 acc[4][4] = {};
  gemm_core(A, B, As, Bs, m0, n0, wm, wn, t, g, c16, acc);
#pragma unroll
  for (int mi = 0; mi < 4; ++mi)
#pragma unroll
    for (int ni = 0; ni < 4; ++ni) {
      int col = n0 + wn + ni * 16 + c16;
      int row = m0 + wm + mi * 16 + g * 4;
      float bv = bias[col];
#pragma unroll
      for (int j = 0; j < 4; ++j)
        C[(size_t)(row + j) * 768 + col] = acc[mi][ni][j] + bv;
    }
}

extern "C" void kernel_launch(void* const* d_in, const int* in_sizes, int n_in,
                              void* d_out, int out_size, void* d_ws, size_t ws_size,
                              hipStream_t stream) {
  const float* q    = (const float*)d_in[0];
  const float* k    = (const float*)d_in[1];
  const float* v    = (const float*)d_in[2];
  const float* mask = (const float*)d_in[3];
  const float* Wq   = (const float*)d_in[4];
  const float* Wk   = (const float*)d_in[5];
  const float* Wv   = (const float*)d_in[6];
  const float* Wp   = (const float*)d_in[7];
  const float* bp   = (const float*)d_in[8];
  float* out = (float*)d_out;

  const size_t MN = (size_t)4096 * 768;   // tokens x channels
  const size_t WW = (size_t)768 * 768;
  unsigned short* qkv_bf = (unsigned short*)d_ws;       // 3*MN
  unsigned short* wt     = qkv_bf + 3 * MN;             // 4*WW (WqT,WkT,WvT,WpT)
  unsigned short* heads  = wt + 4 * WW;                 // qh | kh | vhT, 3*MN
  unsigned short* xb     = heads + 3 * MN;              // attention out, MN

  conv_qkv<<<dim3(3072, 3), 256, 0, stream>>>(q, k, v, qkv_bf);
  conv_w<<<dim3(24, 24, 4), dim3(32, 8), 0, stream>>>(Wq, Wk, Wv, Wp, wt);
  gemm_qkv<<<dim3(6, 32, 3), 256, 0, stream>>>(qkv_bf, wt, heads, heads + MN, heads + 2 * MN);
  attn<<<dim3(16, 12, 4), 256, 0, stream>>>(heads, heads + MN, heads + 2 * MN, mask, xb);
  gemm_proj<<<dim3(6, 32), 256, 0, stream>>>(xb, wt + 3 * WW, bp, out);
}

// Round 3
// 102.848 us; speedup vs baseline: 1.8195x; 1.0888x over previous
//
#include <hip/hip_runtime.h>

typedef __bf16 bf16x8 __attribute__((ext_vector_type(8)));
typedef float f32x4 __attribute__((ext_vector_type(4)));

__device__ __forceinline__ unsigned short f2bf(float f) {
  union { float f; unsigned u; } x; x.f = f;
  unsigned r = x.u + 0x7FFFu + ((x.u >> 16) & 1u);
  return (unsigned short)(r >> 16);
}

// async global->LDS, 16B per lane; LDS dest must be linear (base + lane*16).
__device__ __forceinline__ void gload_lds16(const void* g, void* l) {
  __builtin_amdgcn_global_load_lds(
      (const __attribute__((address_space(1))) unsigned int*)g,
      (__attribute__((address_space(3))) unsigned int*)l, 16, 0, 0);
}

__device__ __forceinline__ f32x4 mfma16(bf16x8 a, bf16x8 b, f32x4 c) {
  return __builtin_amdgcn_mfma_f32_16x16x32_bf16(a, b, c, 0, 0, 0);
}

// ---------------- q,k,v f32 -> bf16 ----------------
__global__ __launch_bounds__(256) void conv_qkv(const float* __restrict__ q,
                                                const float* __restrict__ k,
                                                const float* __restrict__ v,
                                                unsigned short* __restrict__ dst) {
  const float* src = (blockIdx.y == 0) ? q : (blockIdx.y == 1 ? k : v);
  size_t i = ((size_t)blockIdx.x * 256 + threadIdx.x) * 4;
  float4 f = *(const float4*)(src + i);
  ushort4 u;
  u.x = f2bf(f.x); u.y = f2bf(f.y); u.z = f2bf(f.z); u.w = f2bf(f.w);
  *(ushort4*)(dst + (size_t)blockIdx.y * (4096u * 768u) + i) = u;
}

// ---------------- W (768x768 f32) -> Wt[n][k] bf16 ----------------
__global__ __launch_bounds__(256) void conv_w(const float* __restrict__ W0,
                                              const float* __restrict__ W1,
                                              const float* __restrict__ W2,
                                              const float* __restrict__ W3,
                                              unsigned short* __restrict__ Wt) {
  __shared__ float tile[32][33];
  const float* W = (blockIdx.z == 0) ? W0 : (blockIdx.z == 1) ? W1
                   : (blockIdx.z == 2) ? W2 : W3;
  int tx = threadIdx.x, ty = threadIdx.y;  // 32 x 8
  int n0 = blockIdx.x * 32, k0 = blockIdx.y * 32;
#pragma unroll
  for (int i = 0; i < 4; ++i)
    tile[ty * 4 + i][tx] = W[(size_t)(k0 + ty * 4 + i) * 768 + n0 + tx];
  __syncthreads();
  unsigned short* o = Wt + (size_t)blockIdx.z * 768 * 768;
#pragma unroll
  for (int i = 0; i < 4; ++i)
    o[(size_t)(n0 + ty * 4 + i) * 768 + k0 + tx] = f2bf(tile[tx][ty * 4 + i]);
}

// ---------------- shared GEMM mainloop: 64x128 tile, BK=64, double-buffered ----------------
// swizzle: within a 128B row, 16B chunk ch is stored at slot ch ^ ((row>>1)&7).
__device__ __forceinline__ void gemm_core(const unsigned short* __restrict__ A,
                                          const unsigned short* __restrict__ B,
                                          unsigned short (*As)[64 * 64],
                                          unsigned short (*Bs)[128 * 64],
                                          int m0, int n0, int wm, int wn,
                                          int t, int g, int c16,
                                          f32x4 (&acc)[2][4]) {
  auto stageA = [&](unsigned short* dst, int k0) {
#pragma unroll
    for (int i = 0; i < 2; ++i) {
      int fc = i * 256 + t, r = fc >> 3, c = (fc & 7) ^ ((r >> 1) & 7);
      gload_lds16(A + (size_t)(m0 + r) * 768 + k0 + c * 8, (char*)dst + fc * 16);
    }
  };
  auto stageB = [&](unsigned short* dst, int k0) {
#pragma unroll
    for (int i = 0; i < 4; ++i) {
      int fc = i * 256 + t, r = fc >> 3, c = (fc & 7) ^ ((r >> 1) & 7);
      gload_lds16(B + (size_t)(n0 + r) * 768 + k0 + c * 8, (char*)dst + fc * 16);
    }
  };
  stageA(As[0], 0);
  stageB(Bs[0], 0);
  asm volatile("s_waitcnt vmcnt(0)" ::: "memory");
  __syncthreads();
  for (int s = 0; s < 12; ++s) {
    const int cur = s & 1;
    if (s < 11) {
      stageA(As[cur ^ 1], (s + 1) * 64);
      stageB(Bs[cur ^ 1], (s + 1) * 64);
    }
#pragma unroll
    for (int kk = 0; kk < 2; ++kk) {
      const int ch = kk * 4 + g;
      bf16x8 a[2], bw[4];
#pragma unroll
      for (int mi = 0; mi < 2; ++mi) {
        int r = wm + mi * 16 + c16;
        a[mi] = *(const bf16x8*)((char*)As[cur] + r * 128 + (((ch ^ (r >> 1)) & 7) << 4));
      }
#pragma unroll
      for (int ni = 0; ni < 4; ++ni) {
        int r = wn + ni * 16 + c16;
        bw[ni] = *(const bf16x8*)((char*)Bs[cur] + r * 128 + (((ch ^ (r >> 1)) & 7) << 4));
      }
#pragma unroll
      for (int mi = 0; mi < 2; ++mi)
#pragma unroll
        for (int ni = 0; ni < 4; ++ni)
          acc[mi][ni] = mfma16(a[mi], bw[ni], acc[mi][ni]);
    }
    __syncthreads();  // drains vmcnt (next tile staged) + all waves done with cur
  }
}

// ---------------- QKV projections (z=0 qh, z=1 kh, z=2 vh-transposed) ----------------
__global__ __launch_bounds__(256) void gemm_qkv(const unsigned short* __restrict__ Abase,
                                                const unsigned short* __restrict__ Wt,
                                                unsigned short* __restrict__ Hq,
                                                unsigned short* __restrict__ Hk,
                                                unsigned short* __restrict__ Hvt) {
  __shared__ unsigned short As[2][64 * 64], Bs[2][128 * 64];
  const int z = blockIdx.z;
  const unsigned short* A = Abase + (size_t)z * 4096 * 768;
  const unsigned short* B = Wt + (size_t)z * 768 * 768;
  const int t = threadIdx.x, l = t & 63, wid = t >> 6;
  const int g = l >> 4, c16 = l & 15;
  const int m0 = blockIdx.y * 64, n0 = blockIdx.x * 128;
  const int wm = (wid >> 1) * 32, wn = (wid & 1) * 64;
  f32x4 acc[2][4] = {};
  gemm_core(A, B, As, Bs, m0, n0, wm, wn, t, g, c16, acc);
  if (z < 2) {
    unsigned short* C = (z == 0) ? Hq : Hk;
#pragma unroll
    for (int mi = 0; mi < 2; ++mi)
#pragma unroll
      for (int ni = 0; ni < 4; ++ni) {
        int col = n0 + wn + ni * 16 + c16;
        int row = m0 + wm + mi * 16 + g * 4;
#pragma unroll
        for (int j = 0; j < 4; ++j)
          C[(size_t)(row + j) * 768 + col] = f2bf(acc[mi][ni][j]);
      }
  } else {
    // vhT[(b*768 + col)*1024 + m] : head-major rows, sequence contiguous
#pragma unroll
    for (int mi = 0; mi < 2; ++mi) {
      int rowbase = m0 + wm + mi * 16;
      int bat = rowbase >> 10;
      int mloc = (rowbase & 1023) + g * 4;
#pragma unroll
      for (int ni = 0; ni < 4; ++ni) {
        int col = n0 + wn + ni * 16 + c16;
        ushort4 u;
        u.x = f2bf(acc[mi][ni][0]); u.y = f2bf(acc[mi][ni][1]);
        u.z = f2bf(acc[mi][ni][2]); u.w = f2bf(acc[mi][ni][3]);
        *(ushort4*)(Hvt + (((size_t)(bat * 768 + col)) << 10) + mloc) = u;
      }
    }
  }
}

// ---------------- fused attention, QBLK=64, Q in registers, dbuf K/V ----------------
__global__ __launch_bounds__(256) void attn(const unsigned short* __restrict__ qh,
                                            const unsigned short* __restrict__ kh,
                                            const unsigned short* __restrict__ vhT,
                                            const float* __restrict__ mask,
                                            unsigned short* __restrict__ xb) {
  __shared__ unsigned short Ks[2][64 * 64], Vts[2][64 * 64], Ps[4 * 16 * 64];
  const int qt = blockIdx.x, h = blockIdx.y, b = blockIdx.z;
  const int t = threadIdx.x, l = t & 63, wid = t >> 6;
  const int g = l >> 4, c16 = l & 15;

  // Q A-fragments straight to registers (row = qt*64+wid*16+c16, chans kk*32+g*8..+8)
  const unsigned short* qp =
      qh + ((size_t)(b * 1024 + qt * 64 + wid * 16 + c16)) * 768 + h * 64 + g * 8;
  bf16x8 aq0 = *(const bf16x8*)qp;
  bf16x8 aq1 = *(const bf16x8*)(qp + 32);

  // per-lane staging source pointers, advanced each kv tile
  const int fc0 = t, r0 = fc0 >> 3, c0 = (fc0 & 7) ^ ((r0 >> 1) & 7);
  const int fc1 = 256 + t, r1 = fc1 >> 3, c1 = (fc1 & 7) ^ ((r1 >> 1) & 7);
  const unsigned short* kp0 = kh + (size_t)(b * 1024 + r0) * 768 + h * 64 + c0 * 8;
  const unsigned short* kp1 = kh + (size_t)(b * 1024 + r1) * 768 + h * 64 + c1 * 8;
  const unsigned short* vp0 = vhT + ((size_t)(b * 768 + h * 64 + r0)) * 1024 + c0 * 8;
  const unsigned short* vp1 = vhT + ((size_t)(b * 768 + h * 64 + r1)) * 1024 + c1 * 8;
  gload_lds16(kp0, (char*)Ks[0] + fc0 * 16);
  gload_lds16(kp1, (char*)Ks[0] + fc1 * 16);
  gload_lds16(vp0, (char*)Vts[0] + fc0 * 16);
  gload_lds16(vp1, (char*)Vts[0] + fc1 * 16);
  kp0 += 64 * 768; kp1 += 64 * 768; vp0 += 64; vp1 += 64;

  const float* mrow0 =
      mask + ((size_t)(b * 1024 + qt * 64 + wid * 16 + g * 4)) * 1024 + c16;
  const float* mrow1 = mrow0 + 1024;
  const float* mrow2 = mrow0 + 2048;
  const float* mrow3 = mrow0 + 3072;

  asm volatile("s_waitcnt vmcnt(0)" ::: "memory");
  __syncthreads();

  f32x4 o[4] = {};
  float ls[4] = {0.f, 0.f, 0.f, 0.f};
  const float sc = 0.125f * 1.44269504088896341f;  // SCALE * log2(e)
  char* Pw = (char*)Ps + wid * 2048;

  for (int kv = 0; kv < 16; ++kv) {
    const int cur = kv & 1;
    if (kv < 15) {  // stage next K/V tile (overlaps all compute below)
      char* kd = (char*)Ks[cur ^ 1];
      char* vd = (char*)Vts[cur ^ 1];
      gload_lds16(kp0, kd + fc0 * 16);
      gload_lds16(kp1, kd + fc1 * 16);
      gload_lds16(vp0, vd + fc0 * 16);
      gload_lds16(vp1, vd + fc1 * 16);
      kp0 += 64 * 768; kp1 += 64 * 768; vp0 += 64; vp1 += 64;
    }
    // mask tile -> registers (latency hides under QK^T)
    float mreg[4][4];
#pragma unroll
    for (int ni = 0; ni < 4; ++ni) {
      mreg[ni][0] = mrow0[ni * 16];
      mreg[ni][1] = mrow1[ni * 16];
      mreg[ni][2] = mrow2[ni * 16];
      mreg[ni][3] = mrow3[ni * 16];
    }
    mrow0 += 64; mrow1 += 64; mrow2 += 64; mrow3 += 64;
    // S = Q K^T (per wave: 16 q-rows x 64 keys)
    f32x4 p[4] = {};
#pragma unroll
    for (int kk = 0; kk < 2; ++kk) {
      const int ch = kk * 4 + g;
      bf16x8 aq = kk ? aq1 : aq0;
#pragma unroll
      for (int ni = 0; ni < 4; ++ni) {
        int r = ni * 16 + c16;
        bf16x8 bk = *(const bf16x8*)((char*)Ks[cur] + r * 128 + (((ch ^ (r >> 1)) & 7) << 4));
        p[ni] = mfma16(aq, bk, p[ni]);
      }
    }
    // exp (no max-sub: logits*scale <= ~6), per-lane partial row-sum (reduce deferred)
#pragma unroll
    for (int j = 0; j < 4; ++j) {
      float e0 = exp2f(p[0][j] * sc);
      float e1 = exp2f(p[1][j] * sc);
      float e2 = exp2f(p[2][j] * sc);
      float e3 = exp2f(p[3][j] * sc);
      p[0][j] = e0; p[1][j] = e1; p[2][j] = e2; p[3][j] = e3;
      ls[j] += (e0 + e1) + (e2 + e3);
    }
    // post-softmax mask, write P (bf16) into per-wave swizzled LDS
#pragma unroll
    for (int ni = 0; ni < 4; ++ni)
#pragma unroll
      for (int j = 0; j < 4; ++j) {
        float pv = p[ni][j] * mreg[ni][j];
        int row = g * 4 + j, col = ni * 16 + c16;
        *(unsigned short*)(Pw + row * 128 +
                           ((((col >> 3) ^ (row >> 1)) & 7) << 4) + ((col & 7) << 1)) = f2bf(pv);
      }
    asm volatile("s_waitcnt lgkmcnt(0)" ::: "memory");  // own-wave P visibility
    // O += P @ V
#pragma unroll
    for (int kk = 0; kk < 2; ++kk) {
      const int ch = kk * 4 + g;
      bf16x8 ap = *(const bf16x8*)(Pw + c16 * 128 + (((ch ^ (c16 >> 1)) & 7) << 4));
#pragma unroll
      for (int ni = 0; ni < 4; ++ni) {
        int r = ni * 16 + c16;
        bf16x8 bv = *(const bf16x8*)((char*)Vts[cur] + r * 128 + (((ch ^ (r >> 1)) & 7) << 4));
        o[ni] = mfma16(ap, bv, o[ni]);
      }
    }
    __syncthreads();  // next tile staged (vmcnt drained) + all waves done with cur
  }
  // deferred row-sum reduce (16-lane groups share a q-row set)
#pragma unroll
  for (int j = 0; j < 4; ++j) {
    float s = ls[j];
    s += __shfl_xor(s, 1);
    s += __shfl_xor(s, 2);
    s += __shfl_xor(s, 4);
    s += __shfl_xor(s, 8);
    ls[j] = 1.0f / s;
  }
#pragma unroll
  for (int ni = 0; ni < 4; ++ni) {
    int col = h * 64 + ni * 16 + c16;
    int row = qt * 64 + wid * 16 + g * 4;
#pragma unroll
    for (int j = 0; j < 4; ++j)
      xb[((size_t)(b * 1024) + row + j) * 768 + col] = f2bf(o[ni][j] * ls[j]);
  }
}

// ---------------- output projection + bias, f32 out ----------------
__global__ __launch_bounds__(256) void gemm_proj(const unsigned short* __restrict__ A,
                                                 const unsigned short* __restrict__ B,
                                                 const float* __restrict__ bias,
                                                 float* __restrict__ C) {
  __shared__ unsigned short As[2][64 * 64], Bs[2][128 * 64];
  const int t = threadIdx.x, l = t & 63, wid = t >> 6;
  const int g = l >> 4, c16 = l & 15;
  const int m0 = blockIdx.y * 64, n0 = blockIdx.x * 128;
  const int wm = (wid >> 1) * 32, wn = (wid & 1) * 64;
  f32x4 acc[2][4] = {};
  gemm_core(A, B, As, Bs, m0, n0, wm, wn, t, g, c16, acc);
#pragma unroll
  for (int mi = 0; mi < 2; ++mi)
#pragma unroll
    for (int ni = 0; ni < 4; ++ni) {
      int col = n0 + wn + ni * 16 + c16;
      int row = m0 + wm + mi * 16 + g * 4;
      float bv = bias[col];
#pragma unroll
      for (int j = 0; j < 4; ++j)
        C[(size_t)(row + j) * 768 + col] = acc[mi][ni][j] + bv;
    }
}

extern "C" void kernel_launch(void* const* d_in, const int* in_sizes, int n_in,
                              void* d_out, int out_size, void* d_ws, size_t ws_size,
                              hipStream_t stream) {
  const float* q    = (const float*)d_in[0];
  const float* k    = (const float*)d_in[1];
  const float* v    = (const float*)d_in[2];
  const float* mask = (const float*)d_in[3];
  const float* Wq   = (const float*)d_in[4];
  const float* Wk   = (const float*)d_in[5];
  const float* Wv   = (const float*)d_in[6];
  const float* Wp   = (const float*)d_in[7];
  const float* bp   = (const float*)d_in[8];
  float* out = (float*)d_out;

  const size_t MN = (size_t)4096 * 768;   // tokens x channels
  const size_t WW = (size_t)768 * 768;
  unsigned short* qkv_bf = (unsigned short*)d_ws;       // 3*MN
  unsigned short* wt     = qkv_bf + 3 * MN;             // 4*WW (WqT,WkT,WvT,WpT)
  unsigned short* heads  = wt + 4 * WW;                 // qh | kh | vhT, 3*MN
  unsigned short* xb     = heads + 3 * MN;              // attention out, MN

  conv_qkv<<<dim3(3072, 3), 256, 0, stream>>>(q, k, v, qkv_bf);
  conv_w<<<dim3(24, 24, 4), dim3(32, 8), 0, stream>>>(Wq, Wk, Wv, Wp, wt);
  gemm_qkv<<<dim3(6, 64, 3), 256, 0, stream>>>(qkv_bf, wt, heads, heads + MN, heads + 2 * MN);
  attn<<<dim3(16, 12, 4), 256, 0, stream>>>(heads, heads + MN, heads + 2 * MN, mask, xb);
  gemm_proj<<<dim3(6, 64), 256, 0, stream>>>(xb, wt + 3 * WW, bp, out);
}